// Round 4
// baseline (262.163 us; speedup 1.0000x reference)
//
#include <hip/hip_runtime.h>
#include <hip/hip_bf16.h>
#include <cstdint>

#define DD 64
#define NROWS 2097152
#define NBLOCKS 2048
#define TILES_PER_WAVE 16   // 8192 waves * 16 tiles * 16 rows = 2M rows

typedef float f32x4 __attribute__((ext_vector_type(4)));
typedef short bf16x8 __attribute__((ext_vector_type(8)));

static __device__ __forceinline__ short f2bf(float f) {
    union { __hip_bfloat16 b; unsigned short u; } cv;
    cv.b = __float2bfloat16(f);
    return (short)cv.u;
}

// ---------------- prep: K = P @ L @ U, loss = -sum(ulog) ----------------
__global__ void prep_kernel(const float* __restrict__ P,
                            const float* __restrict__ Lm,
                            const float* __restrict__ Um,
                            const float* __restrict__ usign,
                            const float* __restrict__ ulog,
                            float* __restrict__ K,
                            float* __restrict__ loss_out)
{
    __shared__ float Ls[DD][DD];
    __shared__ float Us[DD][DD];
    __shared__ int   pr[DD];
    const int t = threadIdx.x;

    for (int e = t; e < DD * DD; e += blockDim.x) {
        int i = e >> 6, j = e & 63;
        Ls[i][j] = (j < i) ? Lm[e] : (i == j ? 1.0f : 0.0f);
        Us[i][j] = (j > i) ? Um[e] : (i == j ? usign[i] * expf(ulog[i]) : 0.0f);
    }
    if (t < DD) {
        int c = 0;
        for (int j = 0; j < DD; ++j) if (P[t * DD + j] > 0.5f) c = j;
        pr[t] = c;
    }
    __syncthreads();

    for (int e = t; e < DD * DD; e += blockDim.x) {
        int i = e >> 6, j = e & 63;
        const float* lrow = Ls[pr[i]];
        float s = 0.0f;
        #pragma unroll
        for (int k = 0; k < DD; ++k) s = fmaf(lrow[k], Us[k][j], s);
        K[e] = s;
    }
    if (t == 0) {
        double s = 0.0;
        for (int i = 0; i < DD; ++i) s += (double)ulog[i];
        loss_out[0] = (float)(-s);
    }
}

// ---------------- main: out = x @ K via bf16 MFMA ----------------
// 16x16x32 bf16 MFMA, K resident as B-frags in VGPRs.
// Loads: 4-deep register prefetch, exact in-order counted vmcnt (4 loads +
// 4 stores per tile -> steady wait 28).  Stores: MFMA acc staged through a
// per-wave LDS tile (parity double-buffered), read back contiguously and
// written as 4x NT global_store_dwordx4 (1 KB/inst, fillBuffer pattern).
__global__ __launch_bounds__(256, 3) void matmul_kernel(
    const float* __restrict__ x,
    const float* __restrict__ Kg,
    float* __restrict__ out)
{
    __shared__ __align__(16) float stg[4][2][16 * DD];   // 32 KB/block
    const int tid  = threadIdx.x;
    const int lane = tid & 63;
    const int wv   = tid >> 6;
    const long long tile0 = ((long long)blockIdx.x * 4 + wv) * TILES_PER_WAVE;

    const int lrow = lane & 15;   // m (A) / n (B,C) index
    const int kgrp = lane >> 4;   // 0..3 k-group

    // ---- K -> B fragments (once; K is 16 KB, L2-hot) ----
    bf16x8 bfr[2][4];
    #pragma unroll
    for (int kt = 0; kt < 2; ++kt)
        #pragma unroll
        for (int nt = 0; nt < 4; ++nt)
            #pragma unroll
            for (int j = 0; j < 8; ++j)
                bfr[kt][nt][j] = f2bf(Kg[(kt * 32 + kgrp * 8 + j) * DD + nt * 16 + lrow]);
    __builtin_amdgcn_sched_barrier(0);
    asm volatile("s_waitcnt vmcnt(0)" ::: "memory");   // zero the vmcnt base
    __builtin_amdgcn_sched_barrier(0);

    f32x4 b0[4], b1[4], b2[4], b3[4];

    auto LT = [&](long long t, f32x4 (&buf)[4]) {
        const f32x4* p = (const f32x4*)(x + t * 16 * DD + lrow * DD + kgrp * 8);
        buf[0] = p[0];   // kt=0, j=0..3
        buf[1] = p[1];   // kt=0, j=4..7
        buf[2] = p[8];   // kt=1, j=0..3
        buf[3] = p[9];   // kt=1, j=4..7
    };

    auto STEP = [&](int t, f32x4 (&buf)[4], bool doload) {
        // bf16 A-fragments from the prefetched registers
        bf16x8 afr[2];
        #pragma unroll
        for (int kt = 0; kt < 2; ++kt)
            #pragma unroll
            for (int j = 0; j < 8; ++j)
                afr[kt][j] = f2bf(j < 4 ? buf[kt * 2][j] : buf[kt * 2 + 1][j - 4]);

        // refill this register buffer early (anti-dep keeps it after the reads)
        if (doload) LT(tile0 + t + 4, buf);
        __builtin_amdgcn_sched_barrier(0);   // pin: loads above, stores below

        f32x4 acc[4];
        #pragma unroll
        for (int nt = 0; nt < 4; ++nt) acc[nt] = (f32x4){0.f, 0.f, 0.f, 0.f};
        #pragma unroll
        for (int kt = 0; kt < 2; ++kt)
            #pragma unroll
            for (int nt = 0; nt < 4; ++nt)
                acc[nt] = __builtin_amdgcn_mfma_f32_16x16x32_bf16(
                    afr[kt], bfr[kt][nt], acc[nt], 0, 0, 0);

        // stage C-tile in LDS: lane holds out[kgrp*4+r][nt*16+lrow]
        float* tile = &stg[wv][t & 1][0];
        #pragma unroll
        for (int nt = 0; nt < 4; ++nt)
            #pragma unroll
            for (int r = 0; r < 4; ++r)
                tile[(kgrp * 4 + r) * DD + nt * 16 + lrow] = acc[nt][r];

        // contiguous read-back + 1 KB/inst NT stores
        const f32x4* t4 = (const f32x4*)tile;
        f32x4* ob = (f32x4*)(out + (tile0 + t) * 16 * DD);
        #pragma unroll
        for (int i = 0; i < 4; ++i) {
            f32x4 v = t4[i * 64 + lane];
            __builtin_nontemporal_store(v, &ob[i * 64 + lane]);
        }
    };

#define WAITV(W) do { asm volatile("s_waitcnt vmcnt(" #W ")" ::: "memory"); } while (0)
    // Issue order: L0 L1 L2 L3 | [W conv L(t+4) mfma ds S(t)] ...
    // In-order vmcnt at W(t) = #VMEM ops younger than L(t):
    //   t=0:12  t=1:16  t=2:20  t=3:24  t=4..12:28  t=13:20  t=14:20  t=15:16
    LT(tile0 + 0, b0);
    LT(tile0 + 1, b1);
    LT(tile0 + 2, b2);
    LT(tile0 + 3, b3);

    WAITV(12); STEP(0, b0, true);
    WAITV(16); STEP(1, b1, true);
    WAITV(20); STEP(2, b2, true);
    WAITV(24); STEP(3, b3, true);
    for (int tb = 4; tb < 12; tb += 4) {
        WAITV(28); STEP(tb + 0, b0, true);
        WAITV(28); STEP(tb + 1, b1, true);
        WAITV(28); STEP(tb + 2, b2, true);
        WAITV(28); STEP(tb + 3, b3, true);
    }
    WAITV(28); STEP(12, b0, false);
    WAITV(20); STEP(13, b1, false);
    WAITV(20); STEP(14, b2, false);
    WAITV(16); STEP(15, b3, false);
#undef WAITV
}

extern "C" void kernel_launch(void* const* d_in, const int* in_sizes, int n_in,
                              void* d_out, int out_size, void* d_ws, size_t ws_size,
                              hipStream_t stream)
{
    const float* x  = (const float*)d_in[0];
    const float* P  = (const float*)d_in[1];
    const float* Lm = (const float*)d_in[2];
    const float* Um = (const float*)d_in[3];
    const float* sg = (const float*)d_in[4];
    const float* lg = (const float*)d_in[5];
    float* out = (float*)d_out;
    float* K   = (float*)d_ws;   // 64*64*4 = 16 KB scratch

    prep_kernel<<<1, 256, 0, stream>>>(P, Lm, Um, sg, lg, K, out + (size_t)NROWS * DD);
    matmul_kernel<<<NBLOCKS, 256, 0, stream>>>(x, K, out);
}

// Round 5
// 244.739 us; speedup vs baseline: 1.0712x; 1.0712x over previous
//
#include <hip/hip_runtime.h>
#include <hip/hip_bf16.h>
#include <cstdint>

#define DD 64
#define NROWS 2097152
#define NBLOCKS 2048
#define TPW 16   // tiles per wave; 2048 blk * 4 waves * 16 tiles * 16 rows = 2M

typedef float f32x4 __attribute__((ext_vector_type(4)));
typedef short bf16x8 __attribute__((ext_vector_type(8)));

static __device__ __forceinline__ short f2bf(float f) {
    union { __hip_bfloat16 b; unsigned short u; } cv;
    cv.b = __float2bfloat16(f);
    return (short)cv.u;
}

// ---------------- prep: K = P @ L @ U, loss = -sum(ulog) ----------------
__global__ void prep_kernel(const float* __restrict__ P,
                            const float* __restrict__ Lm,
                            const float* __restrict__ Um,
                            const float* __restrict__ usign,
                            const float* __restrict__ ulog,
                            float* __restrict__ K,
                            float* __restrict__ loss_out)
{
    __shared__ float Ls[DD][DD];
    __shared__ float Us[DD][DD];
    __shared__ int   pr[DD];
    const int t = threadIdx.x;

    for (int e = t; e < DD * DD; e += blockDim.x) {
        int i = e >> 6, j = e & 63;
        Ls[i][j] = (j < i) ? Lm[e] : (i == j ? 1.0f : 0.0f);
        Us[i][j] = (j > i) ? Um[e] : (i == j ? usign[i] * expf(ulog[i]) : 0.0f);
    }
    if (t < DD) {
        int c = 0;
        for (int j = 0; j < DD; ++j) if (P[t * DD + j] > 0.5f) c = j;
        pr[t] = c;
    }
    __syncthreads();

    for (int e = t; e < DD * DD; e += blockDim.x) {
        int i = e >> 6, j = e & 63;
        const float* lrow = Ls[pr[i]];
        float s = 0.0f;
        #pragma unroll
        for (int k = 0; k < DD; ++k) s = fmaf(lrow[k], Us[k][j], s);
        K[e] = s;
    }
    if (t == 0) {
        double s = 0.0;
        for (int i = 0; i < DD; ++i) s += (double)ulog[i];
        loss_out[0] = (float)(-s);
    }
}

// ---------------- main: out = x @ K via bf16 MFMA ----------------
// Reads: global_load_lds dwordx4 — contiguous 1 KB/inst (16 lines, each
// touched once), XOR-swizzled SOURCE (chunk c of row r lands at LDS pos c^r,
// linear dest per m104/rule21).  A-frags via 4x ds_read_b128/tile with the
// same XOR on the read — balanced 8 lanes/bank-group (conflict-free b128).
// Per-wave 2-slot LDS ring, no barriers, counted vmcnt.  NT dword stores.
__global__ __launch_bounds__(256, 4) void matmul_kernel(
    const float* __restrict__ x,
    const float* __restrict__ Kg,
    float* __restrict__ out)
{
    __shared__ __align__(16) float stg[4][2][1024];   // 2 x 4KB per wave = 32 KB
    const int tid  = threadIdx.x;
    const int lane = tid & 63;
    const int wv   = tid >> 6;
    const long long tile0 = ((long long)blockIdx.x * 4 + wv) * TPW;

    const int lrow = lane & 15;   // m (A) / n (B,C) index
    const int kgrp = lane >> 4;   // 0..3 k-group

    // ---- K -> B fragments (once; K is 16 KB, L2-hot) ----
    bf16x8 bfr[2][4];
    #pragma unroll
    for (int kt = 0; kt < 2; ++kt)
        #pragma unroll
        for (int nt = 0; nt < 4; ++nt)
            #pragma unroll
            for (int j = 0; j < 8; ++j)
                bfr[kt][nt][j] = f2bf(Kg[(kt * 32 + kgrp * 8 + j) * DD + nt * 16 + lrow]);
    __builtin_amdgcn_sched_barrier(0);
    asm volatile("s_waitcnt vmcnt(0)" ::: "memory");   // zero the vmcnt base
    __builtin_amdgcn_sched_barrier(0);

    // Pre-swizzled per-lane source offsets (floats) for the 4 staging insts:
    // inst i fills LDS (row=4i+kgrp, pos=lrow); that slot must hold chunk
    // c = pos ^ row of that row.
    int soff[4];
    #pragma unroll
    for (int i = 0; i < 4; ++i) {
        int row = 4 * i + kgrp;
        soff[i] = row * 64 + ((lrow ^ row) << 2);
    }

    auto STAGE = [&](int t) {
        const float* gb = x + (tile0 + t) * (16 * DD);
        float* ldst = &stg[wv][t & 1][0];
        #pragma unroll
        for (int i = 0; i < 4; ++i)
            __builtin_amdgcn_global_load_lds(
                (__attribute__((address_space(1))) void*)(gb + soff[i]),
                (__attribute__((address_space(3))) void*)(ldst + i * 256),
                16, 0, 0);
    };

    auto STEP = [&](int t, bool doload) {
        const float* slot = &stg[wv][t & 1][0];
        // A-fragments: chunk c lives at pos c ^ r
        bf16x8 afr[2];
        #pragma unroll
        for (int kt = 0; kt < 2; ++kt) {
            const int c0 = 8 * kt + 2 * kgrp;
            f32x4 lo = *(const f32x4*)(slot + lrow * 64 + (((c0    ) ^ lrow) << 2));
            f32x4 hi = *(const f32x4*)(slot + lrow * 64 + (((c0 + 1) ^ lrow) << 2));
            #pragma unroll
            for (int j = 0; j < 4; ++j) {
                afr[kt][j]     = f2bf(lo[j]);
                afr[kt][4 + j] = f2bf(hi[j]);
            }
        }
        // slot (t&1) is about to be overwritten by tile t+2: ds_reads must
        // have retired before the staging writes can land.
        __builtin_amdgcn_sched_barrier(0);
        asm volatile("s_waitcnt lgkmcnt(0)" ::: "memory");
        __builtin_amdgcn_sched_barrier(0);
        if (doload) STAGE(t + 2);
        __builtin_amdgcn_sched_barrier(0);

        f32x4 acc[4];
        #pragma unroll
        for (int nt = 0; nt < 4; ++nt) acc[nt] = (f32x4){0.f, 0.f, 0.f, 0.f};
        #pragma unroll
        for (int kt = 0; kt < 2; ++kt)
            #pragma unroll
            for (int nt = 0; nt < 4; ++nt)
                acc[nt] = __builtin_amdgcn_mfma_f32_16x16x32_bf16(
                    afr[kt], bfr[kt][nt], acc[nt], 0, 0, 0);

        float* ob = out + (tile0 + t) * (16 * DD) + (kgrp * 4) * DD + lrow;
        #pragma unroll
        for (int nt = 0; nt < 4; ++nt)
            #pragma unroll
            for (int r = 0; r < 4; ++r)
                __builtin_nontemporal_store(acc[nt][r], &ob[r * DD + nt * 16]);
    };

#define WAITV(W) asm volatile("s_waitcnt vmcnt(" #W ")" ::: "memory")
    // VMEM issue order: G0 G1 | [W frag G(t+2) mfma S(t)] ...   (G=4, S=16)
    // In-order vmcnt at W(t) = #VMEM issued after G(t):
    //   t=0: G1 = 4.   t=1: G2,S0 = 20.   t=2..14: S(t-2),G(t+1),S(t-1) = 36.
    //   t=15: S13,S14 = 32.
    STAGE(0);
    STAGE(1);
    WAITV(4);  STEP(0, true);
    WAITV(20); STEP(1, true);
    for (int t = 2; t <= 13; ++t) { WAITV(36); STEP(t, true); }
    WAITV(36); STEP(14, false);
    WAITV(32); STEP(15, false);
#undef WAITV
}

extern "C" void kernel_launch(void* const* d_in, const int* in_sizes, int n_in,
                              void* d_out, int out_size, void* d_ws, size_t ws_size,
                              hipStream_t stream)
{
    const float* x  = (const float*)d_in[0];
    const float* P  = (const float*)d_in[1];
    const float* Lm = (const float*)d_in[2];
    const float* Um = (const float*)d_in[3];
    const float* sg = (const float*)d_in[4];
    const float* lg = (const float*)d_in[5];
    float* out = (float*)d_out;
    float* K   = (float*)d_ws;   // 64*64*4 = 16 KB scratch

    prep_kernel<<<1, 256, 0, stream>>>(P, Lm, Um, sg, lg, K, out + (size_t)NROWS * DD);
    matmul_kernel<<<NBLOCKS, 256, 0, stream>>>(x, K, out);
}

// Round 6
// 239.791 us; speedup vs baseline: 1.0933x; 1.0206x over previous
//
#include <hip/hip_runtime.h>
#include <hip/hip_bf16.h>
#include <cstdint>

#define DD 64
#define NROWS 2097152
#define NBLOCKS 2048
#define TPW 16            // tiles per wave
#define NWAVES 8192       // 2048 blocks * 4 waves
// total tiles = 131072; wave w handles tiles w, w+8192, w+16384, ...
// -> at any instant all resident waves touch a compact sweeping window
//    (copy-kernel row locality) instead of 8192 scattered 4 KB streams.

typedef float f32x4 __attribute__((ext_vector_type(4)));
typedef short bf16x8 __attribute__((ext_vector_type(8)));

static __device__ __forceinline__ short f2bf(float f) {
    union { __hip_bfloat16 b; unsigned short u; } cv;
    cv.b = __float2bfloat16(f);
    return (short)cv.u;
}

// ---------------- prep: K = P @ L @ U, loss = -sum(ulog) ----------------
__global__ void prep_kernel(const float* __restrict__ P,
                            const float* __restrict__ Lm,
                            const float* __restrict__ Um,
                            const float* __restrict__ usign,
                            const float* __restrict__ ulog,
                            float* __restrict__ K,
                            float* __restrict__ loss_out)
{
    __shared__ float Ls[DD][DD];
    __shared__ float Us[DD][DD];
    __shared__ int   pr[DD];
    const int t = threadIdx.x;

    for (int e = t; e < DD * DD; e += blockDim.x) {
        int i = e >> 6, j = e & 63;
        Ls[i][j] = (j < i) ? Lm[e] : (i == j ? 1.0f : 0.0f);
        Us[i][j] = (j > i) ? Um[e] : (i == j ? usign[i] * expf(ulog[i]) : 0.0f);
    }
    if (t < DD) {
        int c = 0;
        for (int j = 0; j < DD; ++j) if (P[t * DD + j] > 0.5f) c = j;
        pr[t] = c;
    }
    __syncthreads();

    for (int e = t; e < DD * DD; e += blockDim.x) {
        int i = e >> 6, j = e & 63;
        const float* lrow = Ls[pr[i]];
        float s = 0.0f;
        #pragma unroll
        for (int k = 0; k < DD; ++k) s = fmaf(lrow[k], Us[k][j], s);
        K[e] = s;
    }
    if (t == 0) {
        double s = 0.0;
        for (int i = 0; i < DD; ++i) s += (double)ulog[i];
        loss_out[0] = (float)(-s);
    }
}

// ---------------- main: out = x @ K via bf16 MFMA ----------------
// R5 structure (global_load_lds 1KB/inst, XOR-swizzled source, conflict-free
// ds_read_b128 frags, 2-slot ring, counted vmcnt, NT dword stores) with ONE
// change: block-strided tile sweep (tile = gwave + t*NWAVES) for DRAM row
// locality.
__global__ __launch_bounds__(256, 4) void matmul_kernel(
    const float* __restrict__ x,
    const float* __restrict__ Kg,
    float* __restrict__ out)
{
    __shared__ __align__(16) float stg[4][2][1024];   // 2 x 4KB per wave = 32 KB
    const int tid  = threadIdx.x;
    const int lane = tid & 63;
    const int wv   = tid >> 6;
    const int gwave = blockIdx.x * 4 + wv;

    const int lrow = lane & 15;   // m (A) / n (B,C) index
    const int kgrp = lane >> 4;   // 0..3 k-group

    // ---- K -> B fragments (once; K is 16 KB, L2-hot) ----
    bf16x8 bfr[2][4];
    #pragma unroll
    for (int kt = 0; kt < 2; ++kt)
        #pragma unroll
        for (int nt = 0; nt < 4; ++nt)
            #pragma unroll
            for (int j = 0; j < 8; ++j)
                bfr[kt][nt][j] = f2bf(Kg[(kt * 32 + kgrp * 8 + j) * DD + nt * 16 + lrow]);
    __builtin_amdgcn_sched_barrier(0);
    asm volatile("s_waitcnt vmcnt(0)" ::: "memory");   // zero the vmcnt base
    __builtin_amdgcn_sched_barrier(0);

    // Pre-swizzled per-lane source offsets: staging inst i fills LDS
    // (row=4i+kgrp, pos=lrow); that slot must hold chunk c = pos ^ row.
    int soff[4];
    #pragma unroll
    for (int i = 0; i < 4; ++i) {
        int row = 4 * i + kgrp;
        soff[i] = row * 64 + ((lrow ^ row) << 2);
    }

    auto TILE = [&](int t) -> long long {
        return (long long)gwave + (long long)t * NWAVES;
    };

    auto STAGE = [&](int t) {
        const float* gb = x + TILE(t) * (16 * DD);
        float* ldst = &stg[wv][t & 1][0];
        #pragma unroll
        for (int i = 0; i < 4; ++i)
            __builtin_amdgcn_global_load_lds(
                (__attribute__((address_space(1))) void*)(gb + soff[i]),
                (__attribute__((address_space(3))) void*)(ldst + i * 256),
                16, 0, 0);
    };

    auto STEP = [&](int t, bool doload) {
        const float* slot = &stg[wv][t & 1][0];
        // A-fragments: chunk c of row r lives at pos c ^ r
        bf16x8 afr[2];
        #pragma unroll
        for (int kt = 0; kt < 2; ++kt) {
            const int c0 = 8 * kt + 2 * kgrp;
            f32x4 lo = *(const f32x4*)(slot + lrow * 64 + (((c0    ) ^ lrow) << 2));
            f32x4 hi = *(const f32x4*)(slot + lrow * 64 + (((c0 + 1) ^ lrow) << 2));
            #pragma unroll
            for (int j = 0; j < 4; ++j) {
                afr[kt][j]     = f2bf(lo[j]);
                afr[kt][4 + j] = f2bf(hi[j]);
            }
        }
        // slot (t&1) is about to be overwritten by tile t+2's staging
        __builtin_amdgcn_sched_barrier(0);
        asm volatile("s_waitcnt lgkmcnt(0)" ::: "memory");
        __builtin_amdgcn_sched_barrier(0);
        if (doload) STAGE(t + 2);
        __builtin_amdgcn_sched_barrier(0);

        f32x4 acc[4];
        #pragma unroll
        for (int nt = 0; nt < 4; ++nt) acc[nt] = (f32x4){0.f, 0.f, 0.f, 0.f};
        #pragma unroll
        for (int kt = 0; kt < 2; ++kt)
            #pragma unroll
            for (int nt = 0; nt < 4; ++nt)
                acc[nt] = __builtin_amdgcn_mfma_f32_16x16x32_bf16(
                    afr[kt], bfr[kt][nt], acc[nt], 0, 0, 0);

        float* ob = out + TILE(t) * (16 * DD) + (kgrp * 4) * DD + lrow;
        #pragma unroll
        for (int nt = 0; nt < 4; ++nt)
            #pragma unroll
            for (int r = 0; r < 4; ++r)
                __builtin_nontemporal_store(acc[nt][r], &ob[r * DD + nt * 16]);
    };

#define WAITV(W) asm volatile("s_waitcnt vmcnt(" #W ")" ::: "memory")
    // VMEM issue order: G0 G1 | [W frag G(t+2) mfma S(t)] ...   (G=4, S=16)
    // In-order vmcnt at W(t) = #VMEM issued after G(t):
    //   t=0: G1 = 4.   t=1: G2,S0 = 20.   t=2..14: S(t-2),G(t+1),S(t-1) = 36.
    //   t=15: S13,S14 = 32.
    STAGE(0);
    STAGE(1);
    WAITV(4);  STEP(0, true);
    WAITV(20); STEP(1, true);
    for (int t = 2; t <= 13; ++t) { WAITV(36); STEP(t, true); }
    WAITV(36); STEP(14, false);
    WAITV(32); STEP(15, false);
#undef WAITV
}

extern "C" void kernel_launch(void* const* d_in, const int* in_sizes, int n_in,
                              void* d_out, int out_size, void* d_ws, size_t ws_size,
                              hipStream_t stream)
{
    const float* x  = (const float*)d_in[0];
    const float* P  = (const float*)d_in[1];
    const float* Lm = (const float*)d_in[2];
    const float* Um = (const float*)d_in[3];
    const float* sg = (const float*)d_in[4];
    const float* lg = (const float*)d_in[5];
    float* out = (float*)d_out;
    float* K   = (float*)d_ws;   // 64*64*4 = 16 KB scratch

    prep_kernel<<<1, 256, 0, stream>>>(P, Lm, Um, sg, lg, K, out + (size_t)NROWS * DD);
    matmul_kernel<<<NBLOCKS, 256, 0, stream>>>(x, K, out);
}

// Round 7
// 234.197 us; speedup vs baseline: 1.1194x; 1.0239x over previous
//
#include <hip/hip_runtime.h>
#include <hip/hip_bf16.h>
#include <cstdint>

#define DD 64
#define NROWS 2097152
#define NBLOCKS 2048
#define TPW 16            // tiles per wave
#define NWAVES 8192       // 2048 blocks * 4 waves
// wave w handles tiles w, w+8192, w+16384, ... (compact sweeping window)

typedef float f32x4 __attribute__((ext_vector_type(4)));
typedef short bf16x8 __attribute__((ext_vector_type(8)));

static __device__ __forceinline__ short f2bf(float f) {
    union { __hip_bfloat16 b; unsigned short u; } cv;
    cv.b = __float2bfloat16(f);
    return (short)cv.u;
}

// ---------------- prep: K = P @ L @ U, loss = -sum(ulog) ----------------
__global__ void prep_kernel(const float* __restrict__ P,
                            const float* __restrict__ Lm,
                            const float* __restrict__ Um,
                            const float* __restrict__ usign,
                            const float* __restrict__ ulog,
                            float* __restrict__ K,
                            float* __restrict__ loss_out)
{
    __shared__ float Ls[DD][DD];
    __shared__ float Us[DD][DD];
    __shared__ int   pr[DD];
    const int t = threadIdx.x;

    for (int e = t; e < DD * DD; e += blockDim.x) {
        int i = e >> 6, j = e & 63;
        Ls[i][j] = (j < i) ? Lm[e] : (i == j ? 1.0f : 0.0f);
        Us[i][j] = (j > i) ? Um[e] : (i == j ? usign[i] * expf(ulog[i]) : 0.0f);
    }
    if (t < DD) {
        int c = 0;
        for (int j = 0; j < DD; ++j) if (P[t * DD + j] > 0.5f) c = j;
        pr[t] = c;
    }
    __syncthreads();

    for (int e = t; e < DD * DD; e += blockDim.x) {
        int i = e >> 6, j = e & 63;
        const float* lrow = Ls[pr[i]];
        float s = 0.0f;
        #pragma unroll
        for (int k = 0; k < DD; ++k) s = fmaf(lrow[k], Us[k][j], s);
        K[e] = s;
    }
    if (t == 0) {
        double s = 0.0;
        for (int i = 0; i < DD; ++i) s += (double)ulog[i];
        loss_out[0] = (float)(-s);
    }
}

// ---------------- main: out = x @ K via bf16 MFMA ----------------
// R6 structure (global_load_lds 1KB/inst staged reads, XOR-swizzled source,
// conflict-free ds_read_b128 frags, 2-slot ring, counted vmcnt, block-strided
// sweep) with ONE change: stores are PLAIN (cached) instead of nontemporal —
// L2 write aggregation + fast store-ack (vmcnt in-order retirement stops
// coupling load-waits to HBM-latency store acks).
__global__ __launch_bounds__(256, 4) void matmul_kernel(
    const float* __restrict__ x,
    const float* __restrict__ Kg,
    float* __restrict__ out)
{
    __shared__ __align__(16) float stg[4][2][1024];   // 2 x 4KB per wave = 32 KB
    const int tid  = threadIdx.x;
    const int lane = tid & 63;
    const int wv   = tid >> 6;
    const int gwave = blockIdx.x * 4 + wv;

    const int lrow = lane & 15;   // m (A) / n (B,C) index
    const int kgrp = lane >> 4;   // 0..3 k-group

    // ---- K -> B fragments (once; K is 16 KB, L2-hot) ----
    bf16x8 bfr[2][4];
    #pragma unroll
    for (int kt = 0; kt < 2; ++kt)
        #pragma unroll
        for (int nt = 0; nt < 4; ++nt)
            #pragma unroll
            for (int j = 0; j < 8; ++j)
                bfr[kt][nt][j] = f2bf(Kg[(kt * 32 + kgrp * 8 + j) * DD + nt * 16 + lrow]);
    __builtin_amdgcn_sched_barrier(0);
    asm volatile("s_waitcnt vmcnt(0)" ::: "memory");   // zero the vmcnt base
    __builtin_amdgcn_sched_barrier(0);

    // Pre-swizzled per-lane source offsets: staging inst i fills LDS
    // (row=4i+kgrp, pos=lrow); that slot must hold chunk c = pos ^ row.
    int soff[4];
    #pragma unroll
    for (int i = 0; i < 4; ++i) {
        int row = 4 * i + kgrp;
        soff[i] = row * 64 + ((lrow ^ row) << 2);
    }

    auto TILE = [&](int t) -> long long {
        return (long long)gwave + (long long)t * NWAVES;
    };

    auto STAGE = [&](int t) {
        const float* gb = x + TILE(t) * (16 * DD);
        float* ldst = &stg[wv][t & 1][0];
        #pragma unroll
        for (int i = 0; i < 4; ++i)
            __builtin_amdgcn_global_load_lds(
                (__attribute__((address_space(1))) void*)(gb + soff[i]),
                (__attribute__((address_space(3))) void*)(ldst + i * 256),
                16, 0, 0);
    };

    auto STEP = [&](int t, bool doload) {
        const float* slot = &stg[wv][t & 1][0];
        // A-fragments: chunk c of row r lives at pos c ^ r
        bf16x8 afr[2];
        #pragma unroll
        for (int kt = 0; kt < 2; ++kt) {
            const int c0 = 8 * kt + 2 * kgrp;
            f32x4 lo = *(const f32x4*)(slot + lrow * 64 + (((c0    ) ^ lrow) << 2));
            f32x4 hi = *(const f32x4*)(slot + lrow * 64 + (((c0 + 1) ^ lrow) << 2));
            #pragma unroll
            for (int j = 0; j < 4; ++j) {
                afr[kt][j]     = f2bf(lo[j]);
                afr[kt][4 + j] = f2bf(hi[j]);
            }
        }
        // slot (t&1) is about to be overwritten by tile t+2's staging
        __builtin_amdgcn_sched_barrier(0);
        asm volatile("s_waitcnt lgkmcnt(0)" ::: "memory");
        __builtin_amdgcn_sched_barrier(0);
        if (doload) STAGE(t + 2);
        __builtin_amdgcn_sched_barrier(0);

        f32x4 acc[4];
        #pragma unroll
        for (int nt = 0; nt < 4; ++nt) acc[nt] = (f32x4){0.f, 0.f, 0.f, 0.f};
        #pragma unroll
        for (int kt = 0; kt < 2; ++kt)
            #pragma unroll
            for (int nt = 0; nt < 4; ++nt)
                acc[nt] = __builtin_amdgcn_mfma_f32_16x16x32_bf16(
                    afr[kt], bfr[kt][nt], acc[nt], 0, 0, 0);

        float* ob = out + TILE(t) * (16 * DD) + (kgrp * 4) * DD + lrow;
        #pragma unroll
        for (int nt = 0; nt < 4; ++nt)
            #pragma unroll
            for (int r = 0; r < 4; ++r)
                ob[r * DD + nt * 16] = acc[nt][r];   // plain cached store
    };

#define WAITV(W) asm volatile("s_waitcnt vmcnt(" #W ")" ::: "memory")
    // VMEM issue order: G0 G1 | [W frag G(t+2) mfma S(t)] ...   (G=4, S=16)
    // In-order vmcnt at W(t) = #VMEM issued after G(t):
    //   t=0: G1 = 4.   t=1: G2,S0 = 20.   t=2..14: S(t-2),G(t+1),S(t-1) = 36.
    //   t=15: S13,S14 = 32.
    STAGE(0);
    STAGE(1);
    WAITV(4);  STEP(0, true);
    WAITV(20); STEP(1, true);
    for (int t = 2; t <= 13; ++t) { WAITV(36); STEP(t, true); }
    WAITV(36); STEP(14, false);
    WAITV(32); STEP(15, false);
#undef WAITV
}

extern "C" void kernel_launch(void* const* d_in, const int* in_sizes, int n_in,
                              void* d_out, int out_size, void* d_ws, size_t ws_size,
                              hipStream_t stream)
{
    const float* x  = (const float*)d_in[0];
    const float* P  = (const float*)d_in[1];
    const float* Lm = (const float*)d_in[2];
    const float* Um = (const float*)d_in[3];
    const float* sg = (const float*)d_in[4];
    const float* lg = (const float*)d_in[5];
    float* out = (float*)d_out;
    float* K   = (float*)d_ws;   // 64*64*4 = 16 KB scratch

    prep_kernel<<<1, 256, 0, stream>>>(P, Lm, Um, sg, lg, K, out + (size_t)NROWS * DD);
    matmul_kernel<<<NBLOCKS, 256, 0, stream>>>(x, K, out);
}

// Round 8
// 229.114 us; speedup vs baseline: 1.1442x; 1.0222x over previous
//
#include <hip/hip_runtime.h>
#include <hip/hip_bf16.h>
#include <cstdint>

#define DD 64
#define NROWS 2097152
#define NBLOCKS 2048
#define TPW 16            // tiles per wave
#define NWAVES 8192       // 2048 blocks * 4 waves
// wave w handles tiles w, w+8192, w+16384, ... (compact sweeping window)

typedef float f32x4 __attribute__((ext_vector_type(4)));
typedef short bf16x8 __attribute__((ext_vector_type(8)));

static __device__ __forceinline__ short f2bf(float f) {
    union { __hip_bfloat16 b; unsigned short u; } cv;
    cv.b = __float2bfloat16(f);
    return (short)cv.u;
}

// ---------------- prep: K = P @ L @ U, loss = -sum(ulog) ----------------
__global__ void prep_kernel(const float* __restrict__ P,
                            const float* __restrict__ Lm,
                            const float* __restrict__ Um,
                            const float* __restrict__ usign,
                            const float* __restrict__ ulog,
                            float* __restrict__ K,
                            float* __restrict__ loss_out)
{
    __shared__ float Ls[DD][DD];
    __shared__ float Us[DD][DD];
    __shared__ int   pr[DD];
    const int t = threadIdx.x;

    for (int e = t; e < DD * DD; e += blockDim.x) {
        int i = e >> 6, j = e & 63;
        Ls[i][j] = (j < i) ? Lm[e] : (i == j ? 1.0f : 0.0f);
        Us[i][j] = (j > i) ? Um[e] : (i == j ? usign[i] * expf(ulog[i]) : 0.0f);
    }
    if (t < DD) {
        int c = 0;
        for (int j = 0; j < DD; ++j) if (P[t * DD + j] > 0.5f) c = j;
        pr[t] = c;
    }
    __syncthreads();

    for (int e = t; e < DD * DD; e += blockDim.x) {
        int i = e >> 6, j = e & 63;
        const float* lrow = Ls[pr[i]];
        float s = 0.0f;
        #pragma unroll
        for (int k = 0; k < DD; ++k) s = fmaf(lrow[k], Us[k][j], s);
        K[e] = s;
    }
    if (t == 0) {
        double s = 0.0;
        for (int i = 0; i < DD; ++i) s += (double)ulog[i];
        loss_out[0] = (float)(-s);
    }
}

// ---------------- main: out = x @ K via bf16 MFMA ----------------
// R7 structure (gload_lds 1KB/inst reads, XOR-swizzled source, conflict-free
// ds_read_b128 frags, 2-slot ring, block-strided sweep, counted vmcnt) with
// ONE change: the C-tile is bounced through a per-wave 4KB LDS buffer and
// written as 4x cached global_store_dwordx4 (1KB contiguous per inst —
// byte-identical store stream to the 6.6 TB/s fillBuffer).
__global__ __launch_bounds__(256, 3) void matmul_kernel(
    const float* __restrict__ x,
    const float* __restrict__ Kg,
    float* __restrict__ out)
{
    __shared__ __align__(16) float stg[4][2][1024];   // input ring: 32 KB
    __shared__ __align__(16) float cbb[4][1024];      // C bounce:   16 KB
    const int tid  = threadIdx.x;
    const int lane = tid & 63;
    const int wv   = tid >> 6;
    const int gwave = blockIdx.x * 4 + wv;

    const int lrow = lane & 15;   // m (A) / n (B,C) index
    const int kgrp = lane >> 4;   // 0..3 k-group

    // ---- K -> B fragments (once; K is 16 KB, L2-hot) ----
    bf16x8 bfr[2][4];
    #pragma unroll
    for (int kt = 0; kt < 2; ++kt)
        #pragma unroll
        for (int nt = 0; nt < 4; ++nt)
            #pragma unroll
            for (int j = 0; j < 8; ++j)
                bfr[kt][nt][j] = f2bf(Kg[(kt * 32 + kgrp * 8 + j) * DD + nt * 16 + lrow]);
    __builtin_amdgcn_sched_barrier(0);
    asm volatile("s_waitcnt vmcnt(0)" ::: "memory");   // zero the vmcnt base
    __builtin_amdgcn_sched_barrier(0);

    // Pre-swizzled per-lane source offsets: staging inst i fills LDS
    // (row=4i+kgrp, pos=lrow); that slot must hold chunk c = pos ^ row.
    int soff[4];
    #pragma unroll
    for (int i = 0; i < 4; ++i) {
        int row = 4 * i + kgrp;
        soff[i] = row * 64 + ((lrow ^ row) << 2);
    }

    auto TILE = [&](int t) -> long long {
        return (long long)gwave + (long long)t * NWAVES;
    };

    auto STAGE = [&](int t) {
        const float* gb = x + TILE(t) * (16 * DD);
        float* ldst = &stg[wv][t & 1][0];
        #pragma unroll
        for (int i = 0; i < 4; ++i)
            __builtin_amdgcn_global_load_lds(
                (__attribute__((address_space(1))) void*)(gb + soff[i]),
                (__attribute__((address_space(3))) void*)(ldst + i * 256),
                16, 0, 0);
    };

    auto STEP = [&](int t, bool doload) {
        const float* slot = &stg[wv][t & 1][0];
        // A-fragments: chunk c of row r lives at pos c ^ r
        bf16x8 afr[2];
        #pragma unroll
        for (int kt = 0; kt < 2; ++kt) {
            const int c0 = 8 * kt + 2 * kgrp;
            f32x4 lo = *(const f32x4*)(slot + lrow * 64 + (((c0    ) ^ lrow) << 2));
            f32x4 hi = *(const f32x4*)(slot + lrow * 64 + (((c0 + 1) ^ lrow) << 2));
            #pragma unroll
            for (int j = 0; j < 4; ++j) {
                afr[kt][j]     = f2bf(lo[j]);
                afr[kt][4 + j] = f2bf(hi[j]);
            }
        }
        // slot (t&1) is about to be overwritten by tile t+2's staging
        __builtin_amdgcn_sched_barrier(0);
        asm volatile("s_waitcnt lgkmcnt(0)" ::: "memory");
        __builtin_amdgcn_sched_barrier(0);
        if (doload) STAGE(t + 2);
        __builtin_amdgcn_sched_barrier(0);

        f32x4 acc[4];
        #pragma unroll
        for (int nt = 0; nt < 4; ++nt) acc[nt] = (f32x4){0.f, 0.f, 0.f, 0.f};
        #pragma unroll
        for (int kt = 0; kt < 2; ++kt)
            #pragma unroll
            for (int nt = 0; nt < 4; ++nt)
                acc[nt] = __builtin_amdgcn_mfma_f32_16x16x32_bf16(
                    afr[kt], bfr[kt][nt], acc[nt], 0, 0, 0);

        // bounce C-tile through LDS (natural row-major layout) ...
        float* bb = &cbb[wv][0];
        #pragma unroll
        for (int nt = 0; nt < 4; ++nt)
            #pragma unroll
            for (int r = 0; r < 4; ++r)
                bb[(kgrp * 4 + r) * DD + nt * 16 + lrow] = acc[nt][r];

        // ... and store as 4x contiguous 1KB dwordx4 (fillBuffer pattern).
        // Per-wave LDS ops are in-order; reg data-deps force the lgkm waits.
        const f32x4* b4 = (const f32x4*)bb;
        f32x4* ob = (f32x4*)(out + TILE(t) * (16 * DD));
        #pragma unroll
        for (int i = 0; i < 4; ++i) {
            f32x4 v = b4[i * 64 + lane];
            ob[i * 64 + lane] = v;   // plain cached store, 1KB/inst
        }
    };

#define WAITV(W) asm volatile("s_waitcnt vmcnt(" #W ")" ::: "memory")
    // VMEM per tile: 4 gload_lds + 4 store_dwordx4.
    // Issue order: G0 G1 | [W frag G(t+2) mfma bounce S(t)] ...
    // In-order vmcnt at W(t) = #VMEM issued after G(t):
    //   t=0: G1 = 4.   t=1: G2,S0 = 8.   t=2..14: S(t-2),G(t+1),S(t-1) = 12.
    //   t=15: S13,S14 = 8.
    STAGE(0);
    STAGE(1);
    WAITV(4);  STEP(0, true);
    WAITV(8);  STEP(1, true);
    for (int t = 2; t <= 13; ++t) { WAITV(12); STEP(t, true); }
    WAITV(12); STEP(14, false);
    WAITV(8);  STEP(15, false);
#undef WAITV
}

extern "C" void kernel_launch(void* const* d_in, const int* in_sizes, int n_in,
                              void* d_out, int out_size, void* d_ws, size_t ws_size,
                              hipStream_t stream)
{
    const float* x  = (const float*)d_in[0];
    const float* P  = (const float*)d_in[1];
    const float* Lm = (const float*)d_in[2];
    const float* Um = (const float*)d_in[3];
    const float* sg = (const float*)d_in[4];
    const float* lg = (const float*)d_in[5];
    float* out = (float*)d_out;
    float* K   = (float*)d_ws;   // 64*64*4 = 16 KB scratch

    prep_kernel<<<1, 256, 0, stream>>>(P, Lm, Um, sg, lg, K, out + (size_t)NROWS * DD);
    matmul_kernel<<<NBLOCKS, 256, 0, stream>>>(x, K, out);
}

// Round 9
// 228.079 us; speedup vs baseline: 1.1494x; 1.0045x over previous
//
#include <hip/hip_runtime.h>
#include <hip/hip_bf16.h>
#include <cstdint>

#define DD 64
#define NROWS 2097152
#define NBLOCKS 2048
#define TPW 16            // tiles per wave
#define NWAVES 8192       // 2048 blocks * 4 waves
// wave w handles tiles w, w+8192, w+16384, ... (compact sweeping window)

typedef float f32x4 __attribute__((ext_vector_type(4)));
typedef short bf16x8 __attribute__((ext_vector_type(8)));

static __device__ __forceinline__ short f2bf(float f) {
    union { __hip_bfloat16 b; unsigned short u; } cv;
    cv.b = __float2bfloat16(f);
    return (short)cv.u;
}

// ---------------- prep: K = P @ L @ U, loss = -sum(ulog) ----------------
__global__ void prep_kernel(const float* __restrict__ P,
                            const float* __restrict__ Lm,
                            const float* __restrict__ Um,
                            const float* __restrict__ usign,
                            const float* __restrict__ ulog,
                            float* __restrict__ K,
                            float* __restrict__ loss_out)
{
    __shared__ float Ls[DD][DD];
    __shared__ float Us[DD][DD];
    __shared__ int   pr[DD];
    const int t = threadIdx.x;

    for (int e = t; e < DD * DD; e += blockDim.x) {
        int i = e >> 6, j = e & 63;
        Ls[i][j] = (j < i) ? Lm[e] : (i == j ? 1.0f : 0.0f);
        Us[i][j] = (j > i) ? Um[e] : (i == j ? usign[i] * expf(ulog[i]) : 0.0f);
    }
    if (t < DD) {
        int c = 0;
        for (int j = 0; j < DD; ++j) if (P[t * DD + j] > 0.5f) c = j;
        pr[t] = c;
    }
    __syncthreads();

    for (int e = t; e < DD * DD; e += blockDim.x) {
        int i = e >> 6, j = e & 63;
        const float* lrow = Ls[pr[i]];
        float s = 0.0f;
        #pragma unroll
        for (int k = 0; k < DD; ++k) s = fmaf(lrow[k], Us[k][j], s);
        K[e] = s;
    }
    if (t == 0) {
        double s = 0.0;
        for (int i = 0; i < DD; ++i) s += (double)ulog[i];
        loss_out[0] = (float)(-s);
    }
}

// ---------------- main: out = x @ K via bf16 MFMA ----------------
// R8 structure with ONE change: the C-tile bounces through the just-consumed
// input ring slot (per-wave DS ops are in-order, so ds_write-after-ds_read on
// the same slot is safe; an lgkmcnt(0) fence guards the DMA re-stage).  LDS
// drops 48->32 KB/block -> 4 blocks/CU (16 waves, +33% TLP).
__global__ __launch_bounds__(256, 4) void matmul_kernel(
    const float* __restrict__ x,
    const float* __restrict__ Kg,
    float* __restrict__ out)
{
    __shared__ __align__(16) float stg[4][2][1024];   // ring (+ C bounce): 32 KB
    const int tid  = threadIdx.x;
    const int lane = tid & 63;
    const int wv   = tid >> 6;
    const int gwave = blockIdx.x * 4 + wv;

    const int lrow = lane & 15;   // m (A) / n (B,C) index
    const int kgrp = lane >> 4;   // 0..3 k-group

    // ---- K -> B fragments (once; K is 16 KB, L2-hot) ----
    bf16x8 bfr[2][4];
    #pragma unroll
    for (int kt = 0; kt < 2; ++kt)
        #pragma unroll
        for (int nt = 0; nt < 4; ++nt)
            #pragma unroll
            for (int j = 0; j < 8; ++j)
                bfr[kt][nt][j] = f2bf(Kg[(kt * 32 + kgrp * 8 + j) * DD + nt * 16 + lrow]);
    __builtin_amdgcn_sched_barrier(0);
    asm volatile("s_waitcnt vmcnt(0)" ::: "memory");   // zero the vmcnt base
    __builtin_amdgcn_sched_barrier(0);

    // Pre-swizzled per-lane source offsets: staging inst i fills LDS
    // (row=4i+kgrp, pos=lrow); that slot must hold chunk c = pos ^ row.
    int soff[4];
    #pragma unroll
    for (int i = 0; i < 4; ++i) {
        int row = 4 * i + kgrp;
        soff[i] = row * 64 + ((lrow ^ row) << 2);
    }

    auto TILE = [&](int t) -> long long {
        return (long long)gwave + (long long)t * NWAVES;
    };

    auto STAGE = [&](int t) {
        const float* gb = x + TILE(t) * (16 * DD);
        float* ldst = &stg[wv][t & 1][0];
        #pragma unroll
        for (int i = 0; i < 4; ++i)
            __builtin_amdgcn_global_load_lds(
                (__attribute__((address_space(1))) void*)(gb + soff[i]),
                (__attribute__((address_space(3))) void*)(ldst + i * 256),
                16, 0, 0);
    };

    auto STEP = [&](int t, bool doload) {
        float* slot = &stg[wv][t & 1][0];
        // A-fragments: chunk c of row r lives at pos c ^ r
        bf16x8 afr[2];
        #pragma unroll
        for (int kt = 0; kt < 2; ++kt) {
            const int c0 = 8 * kt + 2 * kgrp;
            f32x4 lo = *(const f32x4*)(slot + lrow * 64 + (((c0    ) ^ lrow) << 2));
            f32x4 hi = *(const f32x4*)(slot + lrow * 64 + (((c0 + 1) ^ lrow) << 2));
            #pragma unroll
            for (int j = 0; j < 4; ++j) {
                afr[kt][j]     = f2bf(lo[j]);
                afr[kt][4 + j] = f2bf(hi[j]);
            }
        }

        f32x4 acc[4];
        #pragma unroll
        for (int nt = 0; nt < 4; ++nt) acc[nt] = (f32x4){0.f, 0.f, 0.f, 0.f};
        #pragma unroll
        for (int kt = 0; kt < 2; ++kt)
            #pragma unroll
            for (int nt = 0; nt < 4; ++nt)
                acc[nt] = __builtin_amdgcn_mfma_f32_16x16x32_bf16(
                    afr[kt], bfr[kt][nt], acc[nt], 0, 0, 0);

        // bounce C-tile through the just-consumed slot (DS ops are per-wave
        // in-order: these writes execute after the frag reads above) ...
        #pragma unroll
        for (int nt = 0; nt < 4; ++nt)
            #pragma unroll
            for (int r = 0; r < 4; ++r)
                slot[(kgrp * 4 + r) * DD + nt * 16 + lrow] = acc[nt][r];

        // ... read back linearly and store as 4x contiguous 1KB dwordx4.
        const f32x4* b4 = (const f32x4*)slot;
        f32x4* ob = (f32x4*)(out + TILE(t) * (16 * DD));
        #pragma unroll
        for (int i = 0; i < 4; ++i) {
            f32x4 v = b4[i * 64 + lane];
            ob[i * 64 + lane] = v;   // plain cached store, 1KB/inst
        }

        // slot is about to be re-staged for tile t+2: all LDS reads above
        // must have retired before the DMA can land.
        __builtin_amdgcn_sched_barrier(0);
        asm volatile("s_waitcnt lgkmcnt(0)" ::: "memory");
        __builtin_amdgcn_sched_barrier(0);
        if (doload) STAGE(t + 2);
        __builtin_amdgcn_sched_barrier(0);
    };

#define WAITV(W) asm volatile("s_waitcnt vmcnt(" #W ")" ::: "memory")
    // VMEM per STEP(t): [S(t) x4, G(t+2) x4].  Prologue: G0, G1.
    // At STEP(t) we need G(t) complete; ops issued after G(t):
    //   t=0: G1 = 4.   t=1..14: S(t-1),G(t+1) = 8.   t=15: S14 = 4.
    STAGE(0);
    STAGE(1);
    WAITV(4);  STEP(0, true);
    for (int t = 1; t <= 13; ++t) { WAITV(8); STEP(t, true); }
    WAITV(8);  STEP(14, false);
    WAITV(4);  STEP(15, false);
#undef WAITV
}

extern "C" void kernel_launch(void* const* d_in, const int* in_sizes, int n_in,
                              void* d_out, int out_size, void* d_ws, size_t ws_size,
                              hipStream_t stream)
{
    const float* x  = (const float*)d_in[0];
    const float* P  = (const float*)d_in[1];
    const float* Lm = (const float*)d_in[2];
    const float* Um = (const float*)d_in[3];
    const float* sg = (const float*)d_in[4];
    const float* lg = (const float*)d_in[5];
    float* out = (float*)d_out;
    float* K   = (float*)d_ws;   // 64*64*4 = 16 KB scratch

    prep_kernel<<<1, 256, 0, stream>>>(P, Lm, Um, sg, lg, K, out + (size_t)NROWS * DD);
    matmul_kernel<<<NBLOCKS, 256, 0, stream>>>(x, K, out);
}